// Round 1
// baseline (508.004 us; speedup 1.0000x reference)
//
#include <hip/hip_runtime.h>
#include <hip/hip_bf16.h>
#include <math.h>

#define DEV_INLINE __device__ __forceinline__

typedef __attribute__((ext_vector_type(8))) short bf16x8;
typedef __attribute__((ext_vector_type(4))) float f32x4;

// ---------------- helpers ----------------

DEV_INLINE void gload_lds16(const void* g, void* l) {
  // async global->LDS, 16B per lane; LDS dest = wave-uniform base + lane*16
  __builtin_amdgcn_global_load_lds(
      (__attribute__((address_space(1))) unsigned int*)const_cast<void*>(g),
      (__attribute__((address_space(3))) unsigned int*)l,
      16, 0, 0);
}

DEV_INLINE short f2bs(float x) {
  union { __hip_bfloat16 h; short s; } u;
  u.h = __float2bfloat16(x);
  return u.s;
}

DEV_INLINE f32x4 mfma16(bf16x8 a, bf16x8 b, f32x4 c) {
  return __builtin_amdgcn_mfma_f32_16x16x32_bf16(a, b, c, 0, 0, 0);
}

// ---------------- f32 -> bf16 convert ----------------

__global__ __launch_bounds__(256)
void cvt_f32_bf16(const float* __restrict__ in, __hip_bfloat16* __restrict__ out) {
  const size_t i = ((size_t)blockIdx.x * 256 + threadIdx.x) * 4;
  const float4 x = *(const float4*)(in + i);
  union { __hip_bfloat16 h[4]; ushort4 u; } pk;
  pk.h[0] = __float2bfloat16(x.x);
  pk.h[1] = __float2bfloat16(x.y);
  pk.h[2] = __float2bfloat16(x.z);
  pk.h[3] = __float2bfloat16(x.w);
  *(ushort4*)(out + i) = pk.u;
}

// ---------------- weight transpose+convert: W[K][N] f32 -> Wt[N][K] bf16 ----------------

__global__ __launch_bounds__(256)
void transpose_w(const float* __restrict__ W, __hip_bfloat16* __restrict__ Wt, int K, int N) {
  __shared__ float t[32][33];
  const int n0 = blockIdx.x * 32, k0 = blockIdx.y * 32;
  const int tx = threadIdx.x & 31, ty = threadIdx.x >> 5;
#pragma unroll
  for (int r = ty; r < 32; r += 8)
    t[r][tx] = W[(size_t)(k0 + r) * N + n0 + tx];
  __syncthreads();
#pragma unroll
  for (int r = ty; r < 32; r += 8)
    Wt[(size_t)(n0 + r) * K + k0 + tx] = __float2bfloat16(t[tx][r]);
}

// ---------------- GEMM: C = A[M,K] @ Bt[N,K]^T (+bias, +resid/gelu) ----------------
// 128x128 tile, BK=32, 4 waves (2x2), mfma_f32_16x16x32_bf16, global_load_lds staging.
// MODE 0: Cb = bf16(acc + bias)
// MODE 1: Cf = acc + bias + resid   (f32 out)
// MODE 2: Cb = bf16(gelu(acc + bias))   (exact erf gelu)

template<int MODE>
__global__ __launch_bounds__(256)
void gemm_bt(const short* __restrict__ A, const short* __restrict__ Bt,
             const float* __restrict__ bias, const float* __restrict__ resid,
             __hip_bfloat16* __restrict__ Cb, float* __restrict__ Cf,
             int M, int N, int K)
{
  __shared__ short As[128 * 32];
  __shared__ short Bs[128 * 32];
  const int tid = threadIdx.x;
  const int lane = tid & 63;
  const int w = tid >> 6;
  const int q4 = lane >> 4;
  const int c16 = lane & 15;
  const int bm = blockIdx.x * 128;
  const int bn = blockIdx.y * 128;
  const int wm = (w >> 1) * 64;
  const int wn = (w & 1) * 64;

  f32x4 acc[4][4];
#pragma unroll
  for (int i = 0; i < 4; ++i)
#pragma unroll
    for (int j = 0; j < 4; ++j) acc[i][j] = (f32x4){0.f, 0.f, 0.f, 0.f};

  // staging: 512 chunks of 16B per operand; chunk c -> row=c>>2, k8=(c&3)*8
  const int c0 = w * 128 + lane;
  const int r0 = c0 >> 2, k80 = (c0 & 3) * 8;
  const int c1 = c0 + 64;
  const int r1 = c1 >> 2, k81 = (c1 & 3) * 8;

  for (int kt = 0; kt < K; kt += 32) {
    __syncthreads();
    gload_lds16(A  + (size_t)(bm + r0) * K + kt + k80, (char*)As + (size_t)(w * 128 + 0)  * 16);
    gload_lds16(Bt + (size_t)(bn + r0) * K + kt + k80, (char*)Bs + (size_t)(w * 128 + 0)  * 16);
    gload_lds16(A  + (size_t)(bm + r1) * K + kt + k81, (char*)As + (size_t)(w * 128 + 64) * 16);
    gload_lds16(Bt + (size_t)(bn + r1) * K + kt + k81, (char*)Bs + (size_t)(w * 128 + 64) * 16);
    __syncthreads();

    bf16x8 af[4], bfr[4];
#pragma unroll
    for (int mt = 0; mt < 4; ++mt)
      af[mt] = *(const bf16x8*)&As[(wm + mt * 16 + c16) * 32 + q4 * 8];
#pragma unroll
    for (int nt = 0; nt < 4; ++nt)
      bfr[nt] = *(const bf16x8*)&Bs[(wn + nt * 16 + c16) * 32 + q4 * 8];
#pragma unroll
    for (int mt = 0; mt < 4; ++mt)
#pragma unroll
      for (int nt = 0; nt < 4; ++nt)
        acc[mt][nt] = mfma16(af[mt], bfr[nt], acc[mt][nt]);
  }

#pragma unroll
  for (int nt = 0; nt < 4; ++nt) {
    const int col = bn + wn + nt * 16 + c16;
    const float bsv = bias[col];
#pragma unroll
    for (int mt = 0; mt < 4; ++mt) {
      const int row0 = bm + wm + mt * 16 + q4 * 4;
#pragma unroll
      for (int j = 0; j < 4; ++j) {
        float v = acc[mt][nt][j] + bsv;
        const size_t idx = (size_t)(row0 + j) * N + col;
        if constexpr (MODE == 1) {
          Cf[idx] = v + resid[idx];
        } else if constexpr (MODE == 2) {
          v = 0.5f * v * (1.0f + erff(v * 0.70710678118654752f));
          Cb[idx] = __float2bfloat16(v);
        } else {
          Cb[idx] = __float2bfloat16(v);
        }
      }
    }
  }
}

// ---------------- fused flash attention ----------------
// grid = (S/64, H, B), 256 threads = 4 waves, each wave owns 16 q-rows.
// KVBLK=64. K tile via global_load_lds (pre-swizzled source), V tile reg-staged
// transposed into swizzled LDS, P through per-wave swizzled LDS.

__global__ __launch_bounds__(256)
void attn_fused(const short* __restrict__ Q, const short* __restrict__ Kmat,
                const short* __restrict__ V, const float* __restrict__ mask,
                __hip_bfloat16* __restrict__ ctx)
{
  __shared__ short Ksm[64 * 64];     // [kp][dh] rows 128B, xor-swizzled
  __shared__ short Vsm[64 * 64];     // [dh][kp] rows 128B, xor-swizzled
  __shared__ short Psm[4 * 16 * 64]; // per-wave [qrow][kp], swizzled

  const int tid = threadIdx.x;
  const int lane = tid & 63;
  const int w = tid >> 6;
  const int q4 = lane >> 4;
  const int c16 = lane & 15;
  const int b = blockIdx.z;
  const int h = blockIdx.y;
  const int qb = blockIdx.x;

  const size_t rowbase = (size_t)b * 512;
  const int hoff = h * 64;

  // Q fragments: A-frag lane l -> (m = l&15, k = (l>>4)*8 + j); two k-steps over DH=64
  bf16x8 aq[2];
  {
    const size_t qrow = rowbase + (size_t)qb * 64 + w * 16 + c16;
    const short* qp = Q + qrow * 1024 + hoff + q4 * 8;
    aq[0] = *(const bf16x8*)(qp);
    aq[1] = *(const bf16x8*)(qp + 32);
  }

  float m_r[4], l_r[4];
  f32x4 O[4];
#pragma unroll
  for (int j = 0; j < 4; ++j) { m_r[j] = -INFINITY; l_r[j] = 0.f; O[j] = (f32x4){0.f, 0.f, 0.f, 0.f}; }

  // K staging chunks: 512 x 16B, row = 8 chunks
  const int kc0 = w * 128 + lane;
  const int kp0 = kc0 >> 3, kd0 = (kc0 & 7) * 8;
  const int kc1 = kc0 + 64;
  const int kp1 = kc1 >> 3, kd1 = (kc1 & 7) * 8;

  for (int kv0 = 0; kv0 < 512; kv0 += 64) {
    __syncthreads();
    // K tile: linear LDS dest, pre-swizzled global source (element xor on bits 3-5)
    gload_lds16(Kmat + (rowbase + kv0 + kp0) * 1024 + hoff + (kd0 ^ ((kp0 & 7) << 3)),
                (char*)Ksm + (size_t)(w * 128 + 0) * 16);
    gload_lds16(Kmat + (rowbase + kv0 + kp1) * 1024 + hoff + (kd1 ^ ((kp1 & 7) << 3)),
                (char*)Ksm + (size_t)(w * 128 + 64) * 16);
    // V tile transposed into Vsm[dh][kp]
#pragma unroll
    for (int it = 0; it < 2; ++it) {
      const int c = tid + 256 * it;
      const int kp = c >> 3;
      const int dh8 = (c & 7) * 8;
      const bf16x8 vv = *(const bf16x8*)(V + (rowbase + kv0 + kp) * 1024 + hoff + dh8);
#pragma unroll
      for (int j = 0; j < 8; ++j) {
        const int dh = dh8 + j;
        *(short*)((char*)Vsm + dh * 128 + ((kp * 2) ^ ((dh & 7) << 4))) = vv[j];
      }
    }
    __syncthreads();

    // ---- scores ----
    float pv[4][4];
    float mk[4];
#pragma unroll
    for (int t = 0; t < 4; ++t) mk[t] = mask[rowbase + kv0 + t * 16 + c16];
#pragma unroll
    for (int t = 0; t < 4; ++t) {
      f32x4 z = (f32x4){0.f, 0.f, 0.f, 0.f};
      const int kp = t * 16 + c16;
#pragma unroll
      for (int ks = 0; ks < 2; ++ks) {
        const int d = ks * 32 + q4 * 8;
        bf16x8 kf = *(const bf16x8*)((char*)Ksm + kp * 128 + ((d * 2) ^ ((kp & 7) << 4)));
        z = mfma16(aq[ks], kf, z);
      }
#pragma unroll
      for (int j = 0; j < 4; ++j) pv[t][j] = z[j] * 0.125f + mk[t];
    }

    // ---- online softmax per row (row = q4*4 + j, cols across 16 lanes) ----
#pragma unroll
    for (int j = 0; j < 4; ++j) {
      float mt_ = fmaxf(fmaxf(pv[0][j], pv[1][j]), fmaxf(pv[2][j], pv[3][j]));
#pragma unroll
      for (int o = 8; o >= 1; o >>= 1) mt_ = fmaxf(mt_, __shfl_xor(mt_, o));
      const float mn = fmaxf(m_r[j], mt_);
      const float sc = __expf(m_r[j] - mn);
      float rs = 0.f;
#pragma unroll
      for (int t = 0; t < 4; ++t) { const float pe = __expf(pv[t][j] - mn); pv[t][j] = pe; rs += pe; }
#pragma unroll
      for (int o = 8; o >= 1; o >>= 1) rs += __shfl_xor(rs, o);
      l_r[j] = l_r[j] * sc + rs;
      m_r[j] = mn;
#pragma unroll
      for (int nt = 0; nt < 4; ++nt) O[nt][j] *= sc;
    }

    // ---- P to per-wave LDS (swizzled [16][64]) ----
    char* pb = (char*)Psm + w * 2048;
#pragma unroll
    for (int j = 0; j < 4; ++j) {
      const int r = q4 * 4 + j;
#pragma unroll
      for (int t = 0; t < 4; ++t) {
        const int ck = t * 16 + c16;
        *(short*)(pb + r * 128 + ((ck * 2) ^ ((r & 7) << 4))) = f2bs(pv[t][j]);
      }
    }

    // ---- O += P @ V ----
#pragma unroll
    for (int ks = 0; ks < 2; ++ks) {
      const int kk = ks * 32 + q4 * 8;
      bf16x8 pa = *(const bf16x8*)(pb + c16 * 128 + ((kk * 2) ^ ((c16 & 7) << 4)));
#pragma unroll
      for (int nt = 0; nt < 4; ++nt) {
        const int dh = nt * 16 + c16;
        bf16x8 vf = *(const bf16x8*)((char*)Vsm + dh * 128 + ((kk * 2) ^ ((dh & 7) << 4)));
        O[nt] = mfma16(pa, vf, O[nt]);
      }
    }
  }

  float rinv[4];
#pragma unroll
  for (int j = 0; j < 4; ++j) rinv[j] = 1.0f / l_r[j];
#pragma unroll
  for (int nt = 0; nt < 4; ++nt) {
#pragma unroll
    for (int j = 0; j < 4; ++j) {
      const size_t row = rowbase + (size_t)qb * 64 + w * 16 + q4 * 4 + j;
      ctx[row * 1024 + hoff + nt * 16 + c16] = __float2bfloat16(O[nt][j] * rinv[j]);
    }
  }
}

// ---------------- LayerNorm (row per block, D=1024) ----------------

__global__ __launch_bounds__(256)
void ln_kernel(const float* __restrict__ in, const float* __restrict__ gam,
               const float* __restrict__ bet, float* __restrict__ outf,
               __hip_bfloat16* __restrict__ outb)
{
  const int row = blockIdx.x;
  const int tid = threadIdx.x;
  const size_t base = (size_t)row * 1024 + tid * 4;
  const float4 x = *(const float4*)(in + base);
  float s  = x.x + x.y + x.z + x.w;
  float s2 = x.x * x.x + x.y * x.y + x.z * x.z + x.w * x.w;
#pragma unroll
  for (int o = 32; o >= 1; o >>= 1) { s += __shfl_xor(s, o); s2 += __shfl_xor(s2, o); }
  __shared__ float sb[8];
  const int w = tid >> 6;
  if ((tid & 63) == 0) { sb[w] = s; sb[w + 4] = s2; }
  __syncthreads();
  const float ts  = sb[0] + sb[1] + sb[2] + sb[3];
  const float ts2 = sb[4] + sb[5] + sb[6] + sb[7];
  const float mu = ts * (1.0f / 1024.0f);
  const float var = ts2 * (1.0f / 1024.0f) - mu * mu;
  const float rstd = rsqrtf(var + 1e-12f);
  const float4 g4 = *(const float4*)(gam + tid * 4);
  const float4 b4 = *(const float4*)(bet + tid * 4);
  const float y0 = (x.x - mu) * rstd * g4.x + b4.x;
  const float y1 = (x.y - mu) * rstd * g4.y + b4.y;
  const float y2 = (x.z - mu) * rstd * g4.z + b4.z;
  const float y3 = (x.w - mu) * rstd * g4.w + b4.w;
  if (outf) {
    float4 y; y.x = y0; y.y = y1; y.z = y2; y.w = y3;
    *(float4*)(outf + base) = y;
  }
  if (outb) {
    union { __hip_bfloat16 h[4]; ushort4 u; } pk;
    pk.h[0] = __float2bfloat16(y0);
    pk.h[1] = __float2bfloat16(y1);
    pk.h[2] = __float2bfloat16(y2);
    pk.h[3] = __float2bfloat16(y3);
    *(ushort4*)(outb + base) = pk.u;
  }
}

// ---------------- launch ----------------

extern "C" void kernel_launch(void* const* d_in, const int* in_sizes, int n_in,
                              void* d_out, int out_size, void* d_ws, size_t ws_size,
                              hipStream_t stream)
{
  const float* X    = (const float*)d_in[0];
  const float* mask = (const float*)d_in[1];
  const float* Wq   = (const float*)d_in[2];   const float* bq  = (const float*)d_in[3];
  const float* Wk   = (const float*)d_in[4];   const float* bk  = (const float*)d_in[5];
  const float* Wv   = (const float*)d_in[6];   const float* bv  = (const float*)d_in[7];
  const float* Wo   = (const float*)d_in[8];   const float* bo  = (const float*)d_in[9];
  const float* g1   = (const float*)d_in[10];  const float* b1  = (const float*)d_in[11];
  const float* Wi   = (const float*)d_in[12];  const float* bi  = (const float*)d_in[13];
  const float* Wo2  = (const float*)d_in[14];  const float* bo2 = (const float*)d_in[15];
  const float* g2   = (const float*)d_in[16];  const float* b2  = (const float*)d_in[17];
  float* out = (float*)d_out;
  (void)in_sizes; (void)n_in; (void)out_size; (void)ws_size;

  const size_t D = 1024, F = 4096;
  const size_t MN = 8192 * D;

  char* p = (char*)d_ws;
  auto alloc = [&](size_t bytes) { char* r = p; p += (bytes + 255) & ~(size_t)255; return r; };
  short* Xb   = (short*)alloc(MN * 2);        // bf16 X; reused as ctx after QKV
  short* Qb   = (short*)alloc(MN * 2);        // bf16 Q; reused as LN1 bf16 out
  short* Kb   = (short*)alloc(MN * 2);
  short* Vb   = (short*)alloc(MN * 2);
  short* WqT  = (short*)alloc(D * D * 2);
  short* WkT  = (short*)alloc(D * D * 2);
  short* WvT  = (short*)alloc(D * D * 2);
  short* WoT  = (short*)alloc(D * D * 2);
  short* WiT  = (short*)alloc(D * F * 2);
  short* Wo2T = (short*)alloc(D * F * 2);
  float* A1f  = (float*)alloc(MN * 4);        // LN1 f32 out (residual for Wo2)
  short* I1   = (short*)alloc(8192 * F * 2);  // gelu intermediate bf16

  // --- prep: convert X, transpose+convert weights ---
  cvt_f32_bf16<<<dim3((unsigned)(MN / 1024)), 256, 0, stream>>>(X, (__hip_bfloat16*)Xb);
  transpose_w<<<dim3(32, 32),  256, 0, stream>>>(Wq,  (__hip_bfloat16*)WqT,  1024, 1024);
  transpose_w<<<dim3(32, 32),  256, 0, stream>>>(Wk,  (__hip_bfloat16*)WkT,  1024, 1024);
  transpose_w<<<dim3(32, 32),  256, 0, stream>>>(Wv,  (__hip_bfloat16*)WvT,  1024, 1024);
  transpose_w<<<dim3(32, 32),  256, 0, stream>>>(Wo,  (__hip_bfloat16*)WoT,  1024, 1024);
  transpose_w<<<dim3(128, 32), 256, 0, stream>>>(Wi,  (__hip_bfloat16*)WiT,  1024, 4096);
  transpose_w<<<dim3(32, 128), 256, 0, stream>>>(Wo2, (__hip_bfloat16*)Wo2T, 4096, 1024);

  // --- QKV projections ---
  gemm_bt<0><<<dim3(64, 8), 256, 0, stream>>>(Xb, WqT, bq, nullptr, (__hip_bfloat16*)Qb, nullptr, 8192, 1024, 1024);
  gemm_bt<0><<<dim3(64, 8), 256, 0, stream>>>(Xb, WkT, bk, nullptr, (__hip_bfloat16*)Kb, nullptr, 8192, 1024, 1024);
  gemm_bt<0><<<dim3(64, 8), 256, 0, stream>>>(Xb, WvT, bv, nullptr, (__hip_bfloat16*)Vb, nullptr, 8192, 1024, 1024);

  // --- fused attention (ctx overwrites Xb) ---
  attn_fused<<<dim3(8, 16, 16), 256, 0, stream>>>(Qb, Kb, Vb, mask, (__hip_bfloat16*)Xb);

  // --- self-output dense + residual, LN1 ---
  gemm_bt<1><<<dim3(64, 8), 256, 0, stream>>>(Xb, WoT, bo, X, nullptr, out, 8192, 1024, 1024);
  ln_kernel<<<dim3(8192), 256, 0, stream>>>(out, g1, b1, A1f, (__hip_bfloat16*)Qb);

  // --- intermediate dense + gelu ---
  gemm_bt<2><<<dim3(64, 32), 256, 0, stream>>>(Qb, WiT, bi, nullptr, (__hip_bfloat16*)I1, nullptr, 8192, 4096, 1024);

  // --- output dense + residual, LN2 (in-place in d_out) ---
  gemm_bt<1><<<dim3(64, 8), 256, 0, stream>>>(I1, Wo2T, bo2, A1f, nullptr, out, 8192, 1024, 4096);
  ln_kernel<<<dim3(8192), 256, 0, stream>>>(out, g2, b2, out, nullptr);
}

// Round 2
// 481.989 us; speedup vs baseline: 1.0540x; 1.0540x over previous
//
#include <hip/hip_runtime.h>
#include <hip/hip_bf16.h>
#include <math.h>

#define DEV_INLINE __device__ __forceinline__

typedef __attribute__((ext_vector_type(8))) short bf16x8;
typedef __attribute__((ext_vector_type(4))) float f32x4;

// ---------------- helpers ----------------

DEV_INLINE void gload_lds16(const void* g, void* l) {
  // async global->LDS, 16B per lane; LDS dest is wave-uniform base (HW adds lane*16)
  __builtin_amdgcn_global_load_lds(
      (__attribute__((address_space(1))) unsigned int*)const_cast<void*>(g),
      (__attribute__((address_space(3))) unsigned int*)l,
      16, 0, 0);
}

DEV_INLINE unsigned lds_a(const void* p) {
  return (unsigned)(unsigned long long)(__attribute__((address_space(3))) const void*)p;
}

DEV_INLINE short f2bs(float x) {
  union { __hip_bfloat16 h; short s; } u;
  u.h = __float2bfloat16(x);
  return u.s;
}

DEV_INLINE f32x4 mfma16(bf16x8 a, bf16x8 b, f32x4 c) {
  return __builtin_amdgcn_mfma_f32_16x16x32_bf16(a, b, c, 0, 0, 0);
}

// inline-asm ds_read_b128 with compile-time offset (bypasses LLVM lds-dma wait tracking)
#define DSREAD_O(dst, base, imm) \
  asm volatile("ds_read_b128 %0, %1 offset:%2" : "=v"(dst) : "v"(base), "n"(imm))

// ---------------- f32 -> bf16 convert ----------------

__global__ __launch_bounds__(256)
void cvt_f32_bf16(const float* __restrict__ in, __hip_bfloat16* __restrict__ out) {
  const size_t i = ((size_t)blockIdx.x * 256 + threadIdx.x) * 4;
  const float4 x = *(const float4*)(in + i);
  union { __hip_bfloat16 h[4]; ushort4 u; } pk;
  pk.h[0] = __float2bfloat16(x.x);
  pk.h[1] = __float2bfloat16(x.y);
  pk.h[2] = __float2bfloat16(x.z);
  pk.h[3] = __float2bfloat16(x.w);
  *(ushort4*)(out + i) = pk.u;
}

// ---------------- weight transpose+convert: W[K][N] f32 -> Wt[N][K] bf16 ----------------

__global__ __launch_bounds__(256)
void transpose_w(const float* __restrict__ W, __hip_bfloat16* __restrict__ Wt, int K, int N) {
  __shared__ float t[32][33];
  const int n0 = blockIdx.x * 32, k0 = blockIdx.y * 32;
  const int tx = threadIdx.x & 31, ty = threadIdx.x >> 5;
#pragma unroll
  for (int r = ty; r < 32; r += 8)
    t[r][tx] = W[(size_t)(k0 + r) * N + n0 + tx];
  __syncthreads();
#pragma unroll
  for (int r = ty; r < 32; r += 8)
    Wt[(size_t)(n0 + r) * K + k0 + tx] = __float2bfloat16(t[tx][r]);
}

__global__ __launch_bounds__(256)
void concat_bias(const float* __restrict__ a, const float* __restrict__ b,
                 const float* __restrict__ c, float* __restrict__ o) {
  const int i = blockIdx.x * 256 + threadIdx.x;
  o[i] = a[i]; o[1024 + i] = b[i]; o[2048 + i] = c[i];
}

// ---------------- 8-phase pipelined GEMM: C = A[M,K] @ Bt[N,K]^T ----------------
// BN=256 fixed, BM=256 or 128. 512 threads = 8 waves (2M x 4N).
// Ring of 4 LDS regions per operand, each [BM][32] (one 32-wide k-chunk).
// Per phase: ds_read frags -> stage one region -> counted vmcnt -> s_barrier ->
// lgkmcnt(0)+sched_barrier -> setprio(1) + MFMA quadrant + setprio(0) -> s_barrier.
// MODE 0: Cb = bf16(acc+bias); 1: Cf = acc+bias+resid; 2: Cb = bf16(gelu(acc+bias))

template<int BM, int MODE>
__global__ __launch_bounds__(512, 2)
void gemm8p(const short* __restrict__ A, const short* __restrict__ Bt,
            const float* __restrict__ bias, const float* __restrict__ resid,
            __hip_bfloat16* __restrict__ Cb, float* __restrict__ Cf,
            int M, int N, int K)
{
  constexpr int MFR = BM / 32;        // m-frags per wave (8 or 4)
  constexpr int MH  = MFR / 2;        // m-frags per phase (4 or 2)
  constexpr int LA  = BM / 128;       // gloads per A-stage (2 or 1)
  constexpr int LB  = 2;              // gloads per B-stage
  constexpr int ABYTES = BM * 64;     // bytes per A region
  constexpr int NVM = 2 * (LA + LB);  // steady-state vmcnt

  __shared__ short lds[4 * BM * 32 + 4 * 256 * 32];
  short* Areg = lds;
  short* Breg = lds + 4 * BM * 32;

  const int tid  = threadIdx.x;
  const int lane = tid & 63, wid = tid >> 6;
  const int q4 = lane >> 4, c16 = lane & 15;
  const int wm = wid >> 2, wn = wid & 3;

  const int nNT = N >> 8;
  int bid = blockIdx.x;
  { const int cpx = (int)gridDim.x >> 3; bid = (bid & 7) * cpx + (bid >> 3); }
  const int bm = (bid / nNT) * BM;
  const int bn = (bid % nNT) * 256;

  // staging: thread t covers row t>>2, 16B slot t&3 of each region
  const int srow = tid >> 2, ssl = tid & 3;
  const short* Ab = A  + (size_t)(bm + srow) * K + ssl * 8;
  const short* Bb = Bt + (size_t)(bn + srow) * K + ssl * 8;

  // LDS read bases (per-thread, fragment layout)
  const unsigned aRd = lds_a(Areg) + (unsigned)((wm * (BM / 2) + c16) * 64 + q4 * 16);
  const unsigned bRd = lds_a(Breg) + (unsigned)((wn * 64 + c16) * 64 + q4 * 16);

  f32x4 acc[MFR][4];
#pragma unroll
  for (int i = 0; i < MFR; ++i)
#pragma unroll
    for (int j = 0; j < 4; ++j) acc[i][j] = (f32x4){0.f, 0.f, 0.f, 0.f};

  auto stageA = [&](int cs, int reg) {
#pragma unroll
    for (int jj = 0; jj < LA; ++jj)
      gload_lds16(Ab + (size_t)jj * 128 * K + cs * 32,
                  (char*)Areg + reg * ABYTES + jj * 8192 + wid * 1024);
  };
  auto stageB = [&](int cs, int reg) {
#pragma unroll
    for (int jj = 0; jj < LB; ++jj)
      gload_lds16(Bb + (size_t)jj * 128 * K + cs * 32,
                  (char*)Breg + reg * 16384 + jj * 8192 + wid * 1024);
  };

  // prologue: stage chunks 0,1,2 into regions 0,1,2; force chunk 0 landed
#pragma unroll
  for (int c = 0; c < 3; ++c) { stageA(c, c); stageB(c, c); }
  asm volatile("s_waitcnt vmcnt(%0)" :: "n"(NVM));
  __builtin_amdgcn_s_barrier();

  bf16x8 bfr[4];

#define PHASE(G, P, DO_STAGE, NV)                                              \
  {                                                                            \
    constexpr int rr = (P >> 1) & 3;                                           \
    bf16x8 afr[MH];                                                            \
    if constexpr ((P & 1) == 0) {                                              \
      _Pragma("unroll") for (int nf = 0; nf < 4; ++nf)                         \
        DSREAD_O(bfr[nf], bRd, rr * 16384 + nf * 1024);                        \
    }                                                                          \
    _Pragma("unroll") for (int i = 0; i < MH; ++i)                             \
      DSREAD_O(afr[i], aRd, rr * ABYTES + ((P & 1) * MH + i) * 1024);          \
    if (DO_STAGE) {                                                            \
      const int cs = 4 * (G) + 3 + (P >> 1);                                   \
      constexpr int sr = (3 + (P >> 1)) & 3;                                   \
      if constexpr ((P & 1) == 0) stageA(cs, sr); else stageB(cs, sr);         \
    }                                                                          \
    asm volatile("s_waitcnt vmcnt(%0)" :: "n"(NV));                            \
    __builtin_amdgcn_s_barrier();                                              \
    asm volatile("s_waitcnt lgkmcnt(0)");                                      \
    __builtin_amdgcn_sched_barrier(0);                                         \
    __builtin_amdgcn_s_setprio(1);                                             \
    _Pragma("unroll") for (int nf = 0; nf < 4; ++nf)                           \
      _Pragma("unroll") for (int i = 0; i < MH; ++i)                           \
        acc[(P & 1) * MH + i][nf] =                                            \
            mfma16(afr[i], bfr[nf], acc[(P & 1) * MH + i][nf]);                \
    __builtin_amdgcn_s_setprio(0);                                             \
    __builtin_amdgcn_s_barrier();                                              \
  }

  const int NG = K >> 7;  // groups of 4 chunks (128 k)
  for (int g = 0; g < NG - 1; ++g) {
    PHASE(g, 0, true, NVM) PHASE(g, 1, true, NVM)
    PHASE(g, 2, true, NVM) PHASE(g, 3, true, NVM)
    PHASE(g, 4, true, NVM) PHASE(g, 5, true, NVM)
    PHASE(g, 6, true, NVM) PHASE(g, 7, true, NVM)
  }
  { const int g = NG - 1;  // tail: only chunk 4g+3 left to stage; drain
    PHASE(g, 0, true,  NVM)            PHASE(g, 1, true,  NVM)
    PHASE(g, 2, false, (LA + 2 * LB))  PHASE(g, 3, false, (LA + LB))
    PHASE(g, 4, false, LB)             PHASE(g, 5, false, 0)
    PHASE(g, 6, false, 0)              PHASE(g, 7, false, 0)
  }
#undef PHASE

  // epilogue
#pragma unroll
  for (int nf = 0; nf < 4; ++nf) {
    const int col = bn + wn * 64 + nf * 16 + c16;
    const float bsv = bias[col];
#pragma unroll
    for (int mf = 0; mf < MFR; ++mf) {
      const int row0 = bm + wm * (BM / 2) + mf * 16 + q4 * 4;
#pragma unroll
      for (int j = 0; j < 4; ++j) {
        float v = acc[mf][nf][j] + bsv;
        const size_t idx = (size_t)(row0 + j) * N + col;
        if constexpr (MODE == 1) {
          Cf[idx] = v + resid[idx];
        } else if constexpr (MODE == 2) {
          v = 0.5f * v * (1.0f + erff(v * 0.70710678118654752f));
          Cb[idx] = __float2bfloat16(v);
        } else {
          Cb[idx] = __float2bfloat16(v);
        }
      }
    }
  }
}

// ---------------- fused flash attention ----------------
// grid = (S/64, H, B), 256 threads = 4 waves, each wave owns 16 q-rows.
// Q/K/V read from fused QKV buffer with row stride qs (=3072).

__global__ __launch_bounds__(256)
void attn_fused(const short* __restrict__ Q, const short* __restrict__ Kmat,
                const short* __restrict__ V, const float* __restrict__ mask,
                __hip_bfloat16* __restrict__ ctx, int qs)
{
  __shared__ short Ksm[64 * 64];     // [kp][dh] rows 128B, xor-swizzled
  __shared__ short Vsm[64 * 64];     // [dh][kp] rows 128B, xor-swizzled
  __shared__ short Psm[4 * 16 * 64]; // per-wave [qrow][kp], swizzled

  const int tid = threadIdx.x;
  const int lane = tid & 63;
  const int w = tid >> 6;
  const int q4 = lane >> 4;
  const int c16 = lane & 15;
  const int b = blockIdx.z;
  const int h = blockIdx.y;
  const int qb = blockIdx.x;

  const size_t rowbase = (size_t)b * 512;
  const int hoff = h * 64;

  bf16x8 aq[2];
  {
    const size_t qrow = rowbase + (size_t)qb * 64 + w * 16 + c16;
    const short* qp = Q + qrow * qs + hoff + q4 * 8;
    aq[0] = *(const bf16x8*)(qp);
    aq[1] = *(const bf16x8*)(qp + 32);
  }

  float m_r[4], l_r[4];
  f32x4 O[4];
#pragma unroll
  for (int j = 0; j < 4; ++j) { m_r[j] = -INFINITY; l_r[j] = 0.f; O[j] = (f32x4){0.f, 0.f, 0.f, 0.f}; }

  const int kc0 = w * 128 + lane;
  const int kp0 = kc0 >> 3, kd0 = (kc0 & 7) * 8;
  const int kc1 = kc0 + 64;
  const int kp1 = kc1 >> 3, kd1 = (kc1 & 7) * 8;

  for (int kv0 = 0; kv0 < 512; kv0 += 64) {
    __syncthreads();
    gload_lds16(Kmat + (rowbase + kv0 + kp0) * qs + hoff + (kd0 ^ ((kp0 & 7) << 3)),
                (char*)Ksm + (size_t)(w * 128 + 0) * 16);
    gload_lds16(Kmat + (rowbase + kv0 + kp1) * qs + hoff + (kd1 ^ ((kp1 & 7) << 3)),
                (char*)Ksm + (size_t)(w * 128 + 64) * 16);
#pragma unroll
    for (int it = 0; it < 2; ++it) {
      const int c = tid + 256 * it;
      const int kp = c >> 3;
      const int dh8 = (c & 7) * 8;
      const bf16x8 vv = *(const bf16x8*)(V + (rowbase + kv0 + kp) * qs + hoff + dh8);
#pragma unroll
      for (int j = 0; j < 8; ++j) {
        const int dh = dh8 + j;
        *(short*)((char*)Vsm + dh * 128 + ((kp * 2) ^ ((dh & 7) << 4))) = vv[j];
      }
    }
    __syncthreads();

    float pv[4][4];
    float mk[4];
#pragma unroll
    for (int t = 0; t < 4; ++t) mk[t] = mask[rowbase + kv0 + t * 16 + c16];
#pragma unroll
    for (int t = 0; t < 4; ++t) {
      f32x4 z = (f32x4){0.f, 0.f, 0.f, 0.f};
      const int kp = t * 16 + c16;
#pragma unroll
      for (int ks = 0; ks < 2; ++ks) {
        const int d = ks * 32 + q4 * 8;
        bf16x8 kf = *(const bf16x8*)((char*)Ksm + kp * 128 + ((d * 2) ^ ((kp & 7) << 4)));
        z = mfma16(aq[ks], kf, z);
      }
#pragma unroll
      for (int j = 0; j < 4; ++j) pv[t][j] = z[j] * 0.125f + mk[t];
    }

#pragma unroll
    for (int j = 0; j < 4; ++j) {
      float mt_ = fmaxf(fmaxf(pv[0][j], pv[1][j]), fmaxf(pv[2][j], pv[3][j]));
#pragma unroll
      for (int o = 8; o >= 1; o >>= 1) mt_ = fmaxf(mt_, __shfl_xor(mt_, o));
      const float mn = fmaxf(m_r[j], mt_);
      const float sc = __expf(m_r[j] - mn);
      float rs = 0.f;
#pragma unroll
      for (int t = 0; t < 4; ++t) { const float pe = __expf(pv[t][j] - mn); pv[t][j] = pe; rs += pe; }
#pragma unroll
      for (int o = 8; o >= 1; o >>= 1) rs += __shfl_xor(rs, o);
      l_r[j] = l_r[j] * sc + rs;
      m_r[j] = mn;
#pragma unroll
      for (int nt = 0; nt < 4; ++nt) O[nt][j] *= sc;
    }

    char* pb = (char*)Psm + w * 2048;
#pragma unroll
    for (int j = 0; j < 4; ++j) {
      const int r = q4 * 4 + j;
#pragma unroll
      for (int t = 0; t < 4; ++t) {
        const int ck = t * 16 + c16;
        *(short*)(pb + r * 128 + ((ck * 2) ^ ((r & 7) << 4))) = f2bs(pv[t][j]);
      }
    }

#pragma unroll
    for (int ks = 0; ks < 2; ++ks) {
      const int kk = ks * 32 + q4 * 8;
      bf16x8 pa = *(const bf16x8*)(pb + c16 * 128 + ((kk * 2) ^ ((c16 & 7) << 4)));
#pragma unroll
      for (int nt = 0; nt < 4; ++nt) {
        const int dh = nt * 16 + c16;
        bf16x8 vf = *(const bf16x8*)((char*)Vsm + dh * 128 + ((kk * 2) ^ ((dh & 7) << 4)));
        O[nt] = mfma16(pa, vf, O[nt]);
      }
    }
  }

  float rinv[4];
#pragma unroll
  for (int j = 0; j < 4; ++j) rinv[j] = 1.0f / l_r[j];
#pragma unroll
  for (int nt = 0; nt < 4; ++nt) {
#pragma unroll
    for (int j = 0; j < 4; ++j) {
      const size_t row = rowbase + (size_t)qb * 64 + w * 16 + q4 * 4 + j;
      ctx[row * 1024 + hoff + nt * 16 + c16] = __float2bfloat16(O[nt][j] * rinv[j]);
    }
  }
}

// ---------------- LayerNorm (row per block, D=1024) ----------------

__global__ __launch_bounds__(256)
void ln_kernel(const float* __restrict__ in, const float* __restrict__ gam,
               const float* __restrict__ bet, float* __restrict__ outf,
               __hip_bfloat16* __restrict__ outb)
{
  const int row = blockIdx.x;
  const int tid = threadIdx.x;
  const size_t base = (size_t)row * 1024 + tid * 4;
  const float4 x = *(const float4*)(in + base);
  float s  = x.x + x.y + x.z + x.w;
  float s2 = x.x * x.x + x.y * x.y + x.z * x.z + x.w * x.w;
#pragma unroll
  for (int o = 32; o >= 1; o >>= 1) { s += __shfl_xor(s, o); s2 += __shfl_xor(s2, o); }
  __shared__ float sb[8];
  const int w = tid >> 6;
  if ((tid & 63) == 0) { sb[w] = s; sb[w + 4] = s2; }
  __syncthreads();
  const float ts  = sb[0] + sb[1] + sb[2] + sb[3];
  const float ts2 = sb[4] + sb[5] + sb[6] + sb[7];
  const float mu = ts * (1.0f / 1024.0f);
  const float var = ts2 * (1.0f / 1024.0f) - mu * mu;
  const float rstd = rsqrtf(var + 1e-12f);
  const float4 g4 = *(const float4*)(gam + tid * 4);
  const float4 b4 = *(const float4*)(bet + tid * 4);
  const float y0 = (x.x - mu) * rstd * g4.x + b4.x;
  const float y1 = (x.y - mu) * rstd * g4.y + b4.y;
  const float y2 = (x.z - mu) * rstd * g4.z + b4.z;
  const float y3 = (x.w - mu) * rstd * g4.w + b4.w;
  if (outf) {
    float4 y; y.x = y0; y.y = y1; y.z = y2; y.w = y3;
    *(float4*)(outf + base) = y;
  }
  if (outb) {
    union { __hip_bfloat16 h[4]; ushort4 u; } pk;
    pk.h[0] = __float2bfloat16(y0);
    pk.h[1] = __float2bfloat16(y1);
    pk.h[2] = __float2bfloat16(y2);
    pk.h[3] = __float2bfloat16(y3);
    *(ushort4*)(outb + base) = pk.u;
  }
}

// ---------------- launch ----------------

extern "C" void kernel_launch(void* const* d_in, const int* in_sizes, int n_in,
                              void* d_out, int out_size, void* d_ws, size_t ws_size,
                              hipStream_t stream)
{
  const float* X    = (const float*)d_in[0];
  const float* mask = (const float*)d_in[1];
  const float* Wq   = (const float*)d_in[2];   const float* bq  = (const float*)d_in[3];
  const float* Wk   = (const float*)d_in[4];   const float* bk  = (const float*)d_in[5];
  const float* Wv   = (const float*)d_in[6];   const float* bv  = (const float*)d_in[7];
  const float* Wo   = (const float*)d_in[8];   const float* bo  = (const float*)d_in[9];
  const float* g1   = (const float*)d_in[10];  const float* b1  = (const float*)d_in[11];
  const float* Wi   = (const float*)d_in[12];  const float* bi  = (const float*)d_in[13];
  const float* Wo2  = (const float*)d_in[14];  const float* bo2 = (const float*)d_in[15];
  const float* g2   = (const float*)d_in[16];  const float* b2  = (const float*)d_in[17];
  float* out = (float*)d_out;
  (void)in_sizes; (void)n_in; (void)out_size; (void)ws_size;

  const size_t D = 1024, F = 4096;
  const size_t MN = 8192 * D;

  char* p = (char*)d_ws;
  auto alloc = [&](size_t bytes) { char* r = p; p += (bytes + 255) & ~(size_t)255; return r; };
  short* Xb    = (short*)alloc(MN * 2);            // bf16 X; reused as ctx after QKV
  short* QKVb  = (short*)alloc(8192 * 3072 * 2);   // fused QKV out; reused as LN1 bf16
  short* WqkvT = (short*)alloc(3072 * D * 2);      // [3072][1024] bf16
  short* WoT   = (short*)alloc(D * D * 2);
  short* WiT   = (short*)alloc(D * F * 2);
  short* Wo2T  = (short*)alloc(D * F * 2);
  float* bqkv  = (float*)alloc(3072 * 4);
  float* A1f   = (float*)alloc(MN * 4);            // LN1 f32 (residual for Wo2)
  short* I1    = (short*)alloc(8192 * F * 2);      // gelu intermediate bf16

  // --- prep ---
  cvt_f32_bf16<<<dim3((unsigned)(MN / 1024)), 256, 0, stream>>>(X, (__hip_bfloat16*)Xb);
  transpose_w<<<dim3(32, 32),  256, 0, stream>>>(Wq,  (__hip_bfloat16*)(WqkvT + 0),           1024, 1024);
  transpose_w<<<dim3(32, 32),  256, 0, stream>>>(Wk,  (__hip_bfloat16*)(WqkvT + 1024 * 1024), 1024, 1024);
  transpose_w<<<dim3(32, 32),  256, 0, stream>>>(Wv,  (__hip_bfloat16*)(WqkvT + 2048 * 1024), 1024, 1024);
  transpose_w<<<dim3(32, 32),  256, 0, stream>>>(Wo,  (__hip_bfloat16*)WoT,  1024, 1024);
  transpose_w<<<dim3(128, 32), 256, 0, stream>>>(Wi,  (__hip_bfloat16*)WiT,  1024, 4096);
  transpose_w<<<dim3(32, 128), 256, 0, stream>>>(Wo2, (__hip_bfloat16*)Wo2T, 4096, 1024);
  concat_bias<<<dim3(4), 256, 0, stream>>>(bq, bk, bv, bqkv);

  // --- fused QKV projection: [8192,1024] @ [3072,1024]^T -> [8192,3072] ---
  gemm8p<128, 0><<<dim3(768), 512, 0, stream>>>(Xb, WqkvT, bqkv, nullptr,
                                                (__hip_bfloat16*)QKVb, nullptr, 8192, 3072, 1024);

  // --- fused attention (ctx overwrites Xb) ---
  attn_fused<<<dim3(8, 16, 16), 256, 0, stream>>>(QKVb, QKVb + 1024, QKVb + 2048, mask,
                                                  (__hip_bfloat16*)Xb, 3072);

  // --- self-output dense + residual, LN1 ---
  gemm8p<128, 1><<<dim3(256), 512, 0, stream>>>(Xb, WoT, bo, X, nullptr, out, 8192, 1024, 1024);
  ln_kernel<<<dim3(8192), 256, 0, stream>>>(out, g1, b1, A1f, (__hip_bfloat16*)QKVb);

  // --- intermediate dense + gelu ---
  gemm8p<256, 2><<<dim3(512), 512, 0, stream>>>(QKVb, WiT, bi, nullptr,
                                                (__hip_bfloat16*)I1, nullptr, 8192, 4096, 1024);

  // --- output dense + residual, LN2 (in-place in d_out) ---
  gemm8p<128, 1><<<dim3(256), 512, 0, stream>>>(I1, Wo2T, bo2, A1f, nullptr, out, 8192, 1024, 4096);
  ln_kernel<<<dim3(8192), 256, 0, stream>>>(out, g2, b2, out, nullptr);
}

// Round 3
// 478.803 us; speedup vs baseline: 1.0610x; 1.0067x over previous
//
#include <hip/hip_runtime.h>
#include <hip/hip_bf16.h>
#include <math.h>

#define DEV_INLINE __device__ __forceinline__

typedef __attribute__((ext_vector_type(8))) short bf16x8;
typedef __attribute__((ext_vector_type(8))) unsigned short u16x8;
typedef __attribute__((ext_vector_type(4))) float f32x4;

// ---------------- helpers ----------------

DEV_INLINE void gload_lds16(const void* g, void* l) {
  // async global->LDS, 16B per lane; LDS dest is wave-uniform base (HW adds lane*16)
  __builtin_amdgcn_global_load_lds(
      (__attribute__((address_space(1))) unsigned int*)const_cast<void*>(g),
      (__attribute__((address_space(3))) unsigned int*)l,
      16, 0, 0);
}

DEV_INLINE unsigned lds_a(const void* p) {
  return (unsigned)(unsigned long long)(__attribute__((address_space(3))) const void*)p;
}

DEV_INLINE short f2bs(float x) {
  union { __hip_bfloat16 h; short s; } u;
  u.h = __float2bfloat16(x);
  return u.s;
}

DEV_INLINE f32x4 mfma16(bf16x8 a, bf16x8 b, f32x4 c) {
  return __builtin_amdgcn_mfma_f32_16x16x32_bf16(a, b, c, 0, 0, 0);
}

// inline-asm ds_read_b128 with compile-time offset (opaque to LLVM's lds-dma wait logic)
#define DSREAD_O(dst, base, imm) \
  asm volatile("ds_read_b128 %0, %1 offset:%2" : "=v"(dst) : "v"(base), "n"(imm))

// ---------------- f32 -> bf16 convert ----------------

__global__ __launch_bounds__(256)
void cvt_f32_bf16(const float* __restrict__ in, __hip_bfloat16* __restrict__ out) {
  const size_t i = ((size_t)blockIdx.x * 256 + threadIdx.x) * 4;
  const float4 x = *(const float4*)(in + i);
  union { __hip_bfloat16 h[4]; ushort4 u; } pk;
  pk.h[0] = __float2bfloat16(x.x);
  pk.h[1] = __float2bfloat16(x.y);
  pk.h[2] = __float2bfloat16(x.z);
  pk.h[3] = __float2bfloat16(x.w);
  *(ushort4*)(out + i) = pk.u;
}

// ---------------- weight transpose+convert: W[K][N] f32 -> Wt[N][K] bf16 ----------------

__global__ __launch_bounds__(256)
void transpose_w(const float* __restrict__ W, __hip_bfloat16* __restrict__ Wt, int K, int N) {
  __shared__ float t[32][33];
  const int n0 = blockIdx.x * 32, k0 = blockIdx.y * 32;
  const int tx = threadIdx.x & 31, ty = threadIdx.x >> 5;
#pragma unroll
  for (int r = ty; r < 32; r += 8)
    t[r][tx] = W[(size_t)(k0 + r) * N + n0 + tx];
  __syncthreads();
#pragma unroll
  for (int r = ty; r < 32; r += 8)
    Wt[(size_t)(n0 + r) * K + k0 + tx] = __float2bfloat16(t[tx][r]);
}

__global__ __launch_bounds__(256)
void concat_bias(const float* __restrict__ a, const float* __restrict__ b,
                 const float* __restrict__ c, float* __restrict__ o) {
  const int i = blockIdx.x * 256 + threadIdx.x;
  o[i] = a[i]; o[1024 + i] = b[i]; o[2048 + i] = c[i];
}

// ---------------- 8-phase pipelined GEMM: C = A[M,K] @ Bt[N,K]^T ----------------
// BN=256 fixed, BM=256 or 128. 512 threads = 8 waves (2M x 4N).
// Ring of 4 LDS regions per operand, each [BM][32] (one 32-wide k-chunk).
// RAW asm s_barrier (no compiler vmcnt(0) drain) + sched_barrier(0) fences pin
// {ds_read | stage | wait+barrier | MFMA} into their slots. Counted vmcnt only.
// LDS slot swizzle: slot' = slot ^ ((row>>1)&3) via pre-swizzled global source.
// MODE 0: Cb = bf16(acc+bias); 1: Cf = acc+bias+resid; 2: Cb = bf16(gelu(acc+bias))

template<int BM, int MODE>
__global__ __launch_bounds__(512, 2)
void gemm8p(const short* __restrict__ A, const short* __restrict__ Bt,
            const float* __restrict__ bias, const float* __restrict__ resid,
            __hip_bfloat16* __restrict__ Cb, float* __restrict__ Cf,
            int M, int N, int K)
{
  constexpr int MFR = BM / 32;        // m-frags per wave (8 or 4)
  constexpr int MH  = MFR / 2;        // m-frags per phase (4 or 2)
  constexpr int LA  = BM / 128;       // gloads per A-stage (2 or 1)
  constexpr int LB  = 2;              // gloads per B-stage
  constexpr int ABYTES = BM * 64;     // bytes per A region
  constexpr int NVM = 2 * (LA + LB);  // steady-state vmcnt

  __shared__ __align__(128) short lds[4 * BM * 32 + 4 * 256 * 32];
  short* Areg = lds;
  short* Breg = lds + 4 * BM * 32;

  const int tid  = threadIdx.x;
  const int lane = tid & 63, wid = tid >> 6;
  const int q4 = lane >> 4, c16 = lane & 15;
  const int wm = wid >> 2, wn = wid & 3;

  const int nNT = N >> 8;
  int bid = blockIdx.x;
  { const int cpx = (int)gridDim.x >> 3; bid = (bid & 7) * cpx + (bid >> 3); }
  const int bm = (bid / nNT) * BM;
  const int bn = (bid % nNT) * 256;

  // staging: thread t covers row t>>2 of each region; global slot pre-swizzled so
  // LDS (row, s) holds global (row, s ^ ((row>>1)&3))
  const int srow = tid >> 2;
  const int sslg = (tid & 3) ^ ((tid >> 3) & 3);
  const short* Ab = A  + (size_t)(bm + srow) * K + sslg * 8;
  const short* Bb = Bt + (size_t)(bn + srow) * K + sslg * 8;

  // LDS read bases (fragment layout, swizzled slot)
  const int rslot = (q4 ^ ((c16 >> 1) & 3)) * 16;
  const unsigned aRd = lds_a(Areg) + (unsigned)((wm * (BM / 2) + c16) * 64 + rslot);
  const unsigned bRd = lds_a(Breg) + (unsigned)((wn * 64 + c16) * 64 + rslot);

  f32x4 acc[MFR][4];
#pragma unroll
  for (int i = 0; i < MFR; ++i)
#pragma unroll
    for (int j = 0; j < 4; ++j) acc[i][j] = (f32x4){0.f, 0.f, 0.f, 0.f};

  auto stageA = [&](int cs, int reg) {
#pragma unroll
    for (int jj = 0; jj < LA; ++jj)
      gload_lds16(Ab + (size_t)jj * 128 * K + cs * 32,
                  (char*)Areg + reg * ABYTES + jj * 8192 + wid * 1024);
  };
  auto stageB = [&](int cs, int reg) {
#pragma unroll
    for (int jj = 0; jj < LB; ++jj)
      gload_lds16(Bb + (size_t)jj * 128 * K + cs * 32,
                  (char*)Breg + reg * 16384 + jj * 8192 + wid * 1024);
  };

  // prologue: stage chunks 0,1,2 into regions 0,1,2; force chunk 0 landed
#pragma unroll
  for (int c = 0; c < 3; ++c) { stageA(c, c); stageB(c, c); }
  __builtin_amdgcn_sched_barrier(0);
  asm volatile("s_waitcnt vmcnt(%0)" :: "n"(NVM));
  asm volatile("s_barrier");

  bf16x8 bfr[4];

#define PHASE(G, P, DO_STAGE, NV)                                              \
  {                                                                            \
    constexpr int rr = (P >> 1) & 3;                                           \
    bf16x8 afr[MH];                                                            \
    if constexpr ((P & 1) == 0) {                                              \
      _Pragma("unroll") for (int nf = 0; nf < 4; ++nf)                         \
        DSREAD_O(bfr[nf], bRd, rr * 16384 + nf * 1024);                        \
    }                                                                          \
    _Pragma("unroll") for (int i = 0; i < MH; ++i)                             \
      DSREAD_O(afr[i], aRd, rr * ABYTES + ((P & 1) * MH + i) * 1024);          \
    __builtin_amdgcn_sched_barrier(0);                                         \
    if (DO_STAGE) {                                                            \
      const int cs = 4 * (G) + 3 + (P >> 1);                                   \
      constexpr int sr = (3 + (P >> 1)) & 3;                                   \
      if constexpr ((P & 1) == 0) stageA(cs, sr); else stageB(cs, sr);         \
    }                                                                          \
    __builtin_amdgcn_sched_barrier(0);                                         \
    asm volatile("s_waitcnt vmcnt(%0)" :: "n"(NV));                            \
    asm volatile("s_barrier");                                                 \
    asm volatile("s_waitcnt lgkmcnt(0)");                                      \
    __builtin_amdgcn_sched_barrier(0);                                         \
    __builtin_amdgcn_s_setprio(1);                                             \
    _Pragma("unroll") for (int nf = 0; nf < 4; ++nf)                           \
      _Pragma("unroll") for (int i = 0; i < MH; ++i)                           \
        acc[(P & 1) * MH + i][nf] =                                            \
            mfma16(afr[i], bfr[nf], acc[(P & 1) * MH + i][nf]);                \
    __builtin_amdgcn_s_setprio(0);                                             \
    __builtin_amdgcn_sched_barrier(0);                                         \
    asm volatile("s_barrier");                                                 \
  }

  const int NG = K >> 7;  // groups of 4 chunks (128 k)
  for (int g = 0; g < NG - 1; ++g) {
    PHASE(g, 0, true, NVM) PHASE(g, 1, true, NVM)
    PHASE(g, 2, true, NVM) PHASE(g, 3, true, NVM)
    PHASE(g, 4, true, NVM) PHASE(g, 5, true, NVM)
    PHASE(g, 6, true, NVM) PHASE(g, 7, true, NVM)
  }
  { const int g = NG - 1;  // tail: only chunk 4g+3 left to stage; drain counted
    PHASE(g, 0, true,  NVM)       PHASE(g, 1, true,  NVM)
    PHASE(g, 2, false, NVM)       PHASE(g, 3, false, NVM)
    PHASE(g, 4, false, (LA + LB)) PHASE(g, 5, false, (LA + LB))
    PHASE(g, 6, false, 0)         PHASE(g, 7, false, 0)
  }
#undef PHASE

  __builtin_amdgcn_sched_barrier(0);

  // ---- epilogue: per-wave LDS stripe -> coalesced global writes ----
  // (all DMA drained; final phase barrier passed; stripes are wave-private)
  float* eb = (float*)((char*)lds + wid * (16 * 68 * 4));
  const int erow = lane >> 2, ecol = (lane & 3) * 16;
#pragma unroll
  for (int mf = 0; mf < MFR; ++mf) {
#pragma unroll
    for (int nf = 0; nf < 4; ++nf) {
      const int col = bn + wn * 64 + nf * 16 + c16;
      const float bsv = bias[col];
#pragma unroll
      for (int j = 0; j < 4; ++j) {
        float v = acc[mf][nf][j] + bsv;
        if constexpr (MODE == 2)
          v = 0.5f * v * (1.0f + erff(v * 0.70710678118654752f));
        eb[(q4 * 4 + j) * 68 + nf * 16 + c16] = v;
      }
    }
    const int gr = bm + wm * (BM / 2) + mf * 16 + erow;
    const size_t gbase = (size_t)gr * N + bn + wn * 64 + ecol;
    if constexpr (MODE == 1) {
#pragma unroll
      for (int u = 0; u < 4; ++u) {
        float4 t = *(float4*)&eb[erow * 68 + ecol + u * 4];
        const float4 r = *(const float4*)&resid[gbase + u * 4];
        t.x += r.x; t.y += r.y; t.z += r.z; t.w += r.w;
        *(float4*)&Cf[gbase + u * 4] = t;
      }
    } else {
      unsigned short* cp = (unsigned short*)Cb;
#pragma unroll
      for (int u = 0; u < 2; ++u) {
        float4 a = *(float4*)&eb[erow * 68 + ecol + u * 8];
        float4 b = *(float4*)&eb[erow * 68 + ecol + u * 8 + 4];
        u16x8 o;
        o[0] = (unsigned short)f2bs(a.x); o[1] = (unsigned short)f2bs(a.y);
        o[2] = (unsigned short)f2bs(a.z); o[3] = (unsigned short)f2bs(a.w);
        o[4] = (unsigned short)f2bs(b.x); o[5] = (unsigned short)f2bs(b.y);
        o[6] = (unsigned short)f2bs(b.z); o[7] = (unsigned short)f2bs(b.w);
        *(u16x8*)(cp + gbase + u * 8) = o;
      }
    }
  }
}

// ---------------- fused flash attention ----------------
// grid = (S/64, H, B), 256 threads = 4 waves, each wave owns 16 q-rows.
// Q/K/V read from fused QKV buffer with row stride qs (=3072).

__global__ __launch_bounds__(256)
void attn_fused(const short* __restrict__ Q, const short* __restrict__ Kmat,
                const short* __restrict__ V, const float* __restrict__ mask,
                __hip_bfloat16* __restrict__ ctx, int qs)
{
  __shared__ short Ksm[64 * 64];     // [kp][dh] rows 128B, xor-swizzled
  __shared__ short Vsm[64 * 64];     // [dh][kp] rows 128B, xor-swizzled
  __shared__ short Psm[4 * 16 * 64]; // per-wave [qrow][kp], swizzled

  const int tid = threadIdx.x;
  const int lane = tid & 63;
  const int w = tid >> 6;
  const int q4 = lane >> 4;
  const int c16 = lane & 15;
  const int b = blockIdx.z;
  const int h = blockIdx.y;
  const int qb = blockIdx.x;

  const size_t rowbase = (size_t)b * 512;
  const int hoff = h * 64;

  bf16x8 aq[2];
  {
    const size_t qrow = rowbase + (size_t)qb * 64 + w * 16 + c16;
    const short* qp = Q + qrow * qs + hoff + q4 * 8;
    aq[0] = *(const bf16x8*)(qp);
    aq[1] = *(const bf16x8*)(qp + 32);
  }

  float m_r[4], l_r[4];
  f32x4 O[4];
#pragma unroll
  for (int j = 0; j < 4; ++j) { m_r[j] = -INFINITY; l_r[j] = 0.f; O[j] = (f32x4){0.f, 0.f, 0.f, 0.f}; }

  const int kc0 = w * 128 + lane;
  const int kp0 = kc0 >> 3, kd0 = (kc0 & 7) * 8;
  const int kc1 = kc0 + 64;
  const int kp1 = kc1 >> 3, kd1 = (kc1 & 7) * 8;

  for (int kv0 = 0; kv0 < 512; kv0 += 64) {
    __syncthreads();
    gload_lds16(Kmat + (rowbase + kv0 + kp0) * qs + hoff + (kd0 ^ ((kp0 & 7) << 3)),
                (char*)Ksm + (size_t)(w * 128 + 0) * 16);
    gload_lds16(Kmat + (rowbase + kv0 + kp1) * qs + hoff + (kd1 ^ ((kp1 & 7) << 3)),
                (char*)Ksm + (size_t)(w * 128 + 64) * 16);
#pragma unroll
    for (int it = 0; it < 2; ++it) {
      const int c = tid + 256 * it;
      const int kp = c >> 3;
      const int dh8 = (c & 7) * 8;
      const bf16x8 vv = *(const bf16x8*)(V + (rowbase + kv0 + kp) * qs + hoff + dh8);
#pragma unroll
      for (int j = 0; j < 8; ++j) {
        const int dh = dh8 + j;
        *(short*)((char*)Vsm + dh * 128 + ((kp * 2) ^ ((dh & 7) << 4))) = vv[j];
      }
    }
    __syncthreads();

    float pv[4][4];
    float mk[4];
#pragma unroll
    for (int t = 0; t < 4; ++t) mk[t] = mask[rowbase + kv0 + t * 16 + c16];
#pragma unroll
    for (int t = 0; t < 4; ++t) {
      f32x4 z = (f32x4){0.f, 0.f, 0.f, 0.f};
      const int kp = t * 16 + c16;
#pragma unroll
      for (int ks = 0; ks < 2; ++ks) {
        const int d = ks * 32 + q4 * 8;
        bf16x8 kf = *(const bf16x8*)((char*)Ksm + kp * 128 + ((d * 2) ^ ((kp & 7) << 4)));
        z = mfma16(aq[ks], kf, z);
      }
#pragma unroll
      for (int j = 0; j < 4; ++j) pv[t][j] = z[j] * 0.125f + mk[t];
    }

#pragma unroll
    for (int j = 0; j < 4; ++j) {
      float mt_ = fmaxf(fmaxf(pv[0][j], pv[1][j]), fmaxf(pv[2][j], pv[3][j]));
#pragma unroll
      for (int o = 8; o >= 1; o >>= 1) mt_ = fmaxf(mt_, __shfl_xor(mt_, o));
      const float mn = fmaxf(m_r[j], mt_);
      const float sc = __expf(m_r[j] - mn);
      float rs = 0.f;
#pragma unroll
      for (int t = 0; t < 4; ++t) { const float pe = __expf(pv[t][j] - mn); pv[t][j] = pe; rs += pe; }
#pragma unroll
      for (int o = 8; o >= 1; o >>= 1) rs += __shfl_xor(rs, o);
      l_r[j] = l_r[j] * sc + rs;
      m_r[j] = mn;
#pragma unroll
      for (int nt = 0; nt < 4; ++nt) O[nt][j] *= sc;
    }

    char* pb = (char*)Psm + w * 2048;
#pragma unroll
    for (int j = 0; j < 4; ++j) {
      const int r = q4 * 4 + j;
#pragma unroll
      for (int t = 0; t < 4; ++t) {
        const int ck = t * 16 + c16;
        *(short*)(pb + r * 128 + ((ck * 2) ^ ((r & 7) << 4))) = f2bs(pv[t][j]);
      }
    }

#pragma unroll
    for (int ks = 0; ks < 2; ++ks) {
      const int kk = ks * 32 + q4 * 8;
      bf16x8 pa = *(const bf16x8*)(pb + c16 * 128 + ((kk * 2) ^ ((c16 & 7) << 4)));
#pragma unroll
      for (int nt = 0; nt < 4; ++nt) {
        const int dh = nt * 16 + c16;
        bf16x8 vf = *(const bf16x8*)((char*)Vsm + dh * 128 + ((kk * 2) ^ ((dh & 7) << 4)));
        O[nt] = mfma16(pa, vf, O[nt]);
      }
    }
  }

  float rinv[4];
#pragma unroll
  for (int j = 0; j < 4; ++j) rinv[j] = 1.0f / l_r[j];
#pragma unroll
  for (int nt = 0; nt < 4; ++nt) {
#pragma unroll
    for (int j = 0; j < 4; ++j) {
      const size_t row = rowbase + (size_t)qb * 64 + w * 16 + q4 * 4 + j;
      ctx[row * 1024 + hoff + nt * 16 + c16] = __float2bfloat16(O[nt][j] * rinv[j]);
    }
  }
}

// ---------------- LayerNorm (row per block, D=1024) ----------------

__global__ __launch_bounds__(256)
void ln_kernel(const float* __restrict__ in, const float* __restrict__ gam,
               const float* __restrict__ bet, float* __restrict__ outf,
               __hip_bfloat16* __restrict__ outb)
{
  const int row = blockIdx.x;
  const int tid = threadIdx.x;
  const size_t base = (size_t)row * 1024 + tid * 4;
  const float4 x = *(const float4*)(in + base);
  float s  = x.x + x.y + x.z + x.w;
  float s2 = x.x * x.x + x.y * x.y + x.z * x.z + x.w * x.w;
#pragma unroll
  for (int o = 32; o >= 1; o >>= 1) { s += __shfl_xor(s, o); s2 += __shfl_xor(s2, o); }
  __shared__ float sb[8];
  const int w = tid >> 6;
  if ((tid & 63) == 0) { sb[w] = s; sb[w + 4] = s2; }
  __syncthreads();
  const float ts  = sb[0] + sb[1] + sb[2] + sb[3];
  const float ts2 = sb[4] + sb[5] + sb[6] + sb[7];
  const float mu = ts * (1.0f / 1024.0f);
  const float var = ts2 * (1.0f / 1024.0f) - mu * mu;
  const float rstd = rsqrtf(var + 1e-12f);
  const float4 g4 = *(const float4*)(gam + tid * 4);
  const float4 b4 = *(const float4*)(bet + tid * 4);
  const float y0 = (x.x - mu) * rstd * g4.x + b4.x;
  const float y1 = (x.y - mu) * rstd * g4.y + b4.y;
  const float y2 = (x.z - mu) * rstd * g4.z + b4.z;
  const float y3 = (x.w - mu) * rstd * g4.w + b4.w;
  if (outf) {
    float4 y; y.x = y0; y.y = y1; y.z = y2; y.w = y3;
    *(float4*)(outf + base) = y;
  }
  if (outb) {
    union { __hip_bfloat16 h[4]; ushort4 u; } pk;
    pk.h[0] = __float2bfloat16(y0);
    pk.h[1] = __float2bfloat16(y1);
    pk.h[2] = __float2bfloat16(y2);
    pk.h[3] = __float2bfloat16(y3);
    *(ushort4*)(outb + base) = pk.u;
  }
}

// ---------------- launch ----------------

extern "C" void kernel_launch(void* const* d_in, const int* in_sizes, int n_in,
                              void* d_out, int out_size, void* d_ws, size_t ws_size,
                              hipStream_t stream)
{
  const float* X    = (const float*)d_in[0];
  const float* mask = (const float*)d_in[1];
  const float* Wq   = (const float*)d_in[2];   const float* bq  = (const float*)d_in[3];
  const float* Wk   = (const float*)d_in[4];   const float* bk  = (const float*)d_in[5];
  const float* Wv   = (const float*)d_in[6];   const float* bv  = (const float*)d_in[7];
  const float* Wo   = (const float*)d_in[8];   const float* bo  = (const float*)d_in[9];
  const float* g1   = (const float*)d_in[10];  const float* b1  = (const float*)d_in[11];
  const float* Wi   = (const float*)d_in[12];  const float* bi  = (const float*)d_in[13];
  const float* Wo2  = (const float*)d_in[14];  const float* bo2 = (const float*)d_in[15];
  const float* g2   = (const float*)d_in[16];  const float* b2  = (const float*)d_in[17];
  float* out = (float*)d_out;
  (void)in_sizes; (void)n_in; (void)out_size; (void)ws_size;

  const size_t D = 1024, F = 4096;
  const size_t MN = 8192 * D;

  char* p = (char*)d_ws;
  auto alloc = [&](size_t bytes) { char* r = p; p += (bytes + 255) & ~(size_t)255; return r; };
  short* Xb    = (short*)alloc(MN * 2);            // bf16 X; reused as ctx after QKV
  short* QKVb  = (short*)alloc(8192 * 3072 * 2);   // fused QKV out; reused as LN1 bf16
  short* WqkvT = (short*)alloc(3072 * D * 2);      // [3072][1024] bf16
  short* WoT   = (short*)alloc(D * D * 2);
  short* WiT   = (short*)alloc(D * F * 2);
  short* Wo2T  = (short*)alloc(D * F * 2);
  float* bqkv  = (float*)alloc(3072 * 4);
  float* A1f   = (float*)alloc(MN * 4);            // LN1 f32 (residual for Wo2)
  short* I1    = (short*)alloc(8192 * F * 2);      // gelu intermediate bf16

  // --- prep ---
  cvt_f32_bf16<<<dim3((unsigned)(MN / 1024)), 256, 0, stream>>>(X, (__hip_bfloat16*)Xb);
  transpose_w<<<dim3(32, 32),  256, 0, stream>>>(Wq,  (__hip_bfloat16*)(WqkvT + 0),           1024, 1024);
  transpose_w<<<dim3(32, 32),  256, 0, stream>>>(Wk,  (__hip_bfloat16*)(WqkvT + 1024 * 1024), 1024, 1024);
  transpose_w<<<dim3(32, 32),  256, 0, stream>>>(Wv,  (__hip_bfloat16*)(WqkvT + 2048 * 1024), 1024, 1024);
  transpose_w<<<dim3(32, 32),  256, 0, stream>>>(Wo,  (__hip_bfloat16*)WoT,  1024, 1024);
  transpose_w<<<dim3(128, 32), 256, 0, stream>>>(Wi,  (__hip_bfloat16*)WiT,  1024, 4096);
  transpose_w<<<dim3(32, 128), 256, 0, stream>>>(Wo2, (__hip_bfloat16*)Wo2T, 4096, 1024);
  concat_bias<<<dim3(4), 256, 0, stream>>>(bq, bk, bv, bqkv);

  // --- fused QKV projection: [8192,1024] @ [3072,1024]^T -> [8192,3072] ---
  gemm8p<128, 0><<<dim3(768), 512, 0, stream>>>(Xb, WqkvT, bqkv, nullptr,
                                                (__hip_bfloat16*)QKVb, nullptr, 8192, 3072, 1024);

  // --- fused attention (ctx overwrites Xb) ---
  attn_fused<<<dim3(8, 16, 16), 256, 0, stream>>>(QKVb, QKVb + 1024, QKVb + 2048, mask,
                                                  (__hip_bfloat16*)Xb, 3072);

  // --- self-output dense + residual, LN1 ---
  gemm8p<128, 1><<<dim3(256), 512, 0, stream>>>(Xb, WoT, bo, X, nullptr, out, 8192, 1024, 1024);
  ln_kernel<<<dim3(8192), 256, 0, stream>>>(out, g1, b1, A1f, (__hip_bfloat16*)QKVb);

  // --- intermediate dense + gelu ---
  gemm8p<256, 2><<<dim3(512), 512, 0, stream>>>(QKVb, WiT, bi, nullptr,
                                                (__hip_bfloat16*)I1, nullptr, 8192, 4096, 1024);

  // --- output dense + residual, LN2 (in-place in d_out) ---
  gemm8p<128, 1><<<dim3(256), 512, 0, stream>>>(I1, Wo2T, bo2, A1f, nullptr, out, 8192, 1024, 4096);
  ln_kernel<<<dim3(8192), 256, 0, stream>>>(out, g2, b2, out, nullptr);
}